// Round 1
// baseline (845.559 us; speedup 1.0000x reference)
//
#include <hip/hip_runtime.h>
#include <hip/hip_bf16.h>

// Grid (voxel) mean pooling, packed single-batch mode.
// x in [0,1)^3 -> voxel = floor(x*20) in [0,20)^3 -> <= 8000 bins.
// Reference hash ((v0-m0)*d1 + (v1-m1))*d2 + (v2-m2) is monotone-lexicographic
// and injective over the occupied range, as is our raw hash (v0*20+v1)*20+v2,
// so grouping AND sorted-unique order are identical -> no min/max pass needed.

#define NBINS 8000
#define NBINS_PAD 8192   // scan padding (1024 threads x 8 items)

__global__ void accum_kernel(const float* __restrict__ x, int N,
                             float* __restrict__ sx, float* __restrict__ sy,
                             float* __restrict__ sz, float* __restrict__ cn) {
    const float scale = (float)(1.0 / 0.05);   // == 20.0f in fp32
    int t = blockIdx.x * blockDim.x + threadIdx.x;
    long long base = (long long)t * 4;
    if (base >= N) return;

    float px[4], py[4], pz[4];
    int npts;
    if (base + 4 <= N) {
        const float4* xv = (const float4*)x;
        float4 a = xv[3 * (size_t)t + 0];
        float4 b = xv[3 * (size_t)t + 1];
        float4 c = xv[3 * (size_t)t + 2];
        px[0] = a.x; py[0] = a.y; pz[0] = a.z;
        px[1] = a.w; py[1] = b.x; pz[1] = b.y;
        px[2] = b.z; py[2] = b.w; pz[2] = c.x;
        px[3] = c.y; py[3] = c.z; pz[3] = c.w;
        npts = 4;
    } else {
        npts = (int)(N - base);
        for (int j = 0; j < npts; ++j) {
            px[j] = x[3 * (base + j) + 0];
            py[j] = x[3 * (base + j) + 1];
            pz[j] = x[3 * (base + j) + 2];
        }
    }

    #pragma unroll
    for (int j = 0; j < 4; ++j) {
        if (j >= npts) break;
        int vx = (int)floorf(px[j] * scale);
        int vy = (int)floorf(py[j] * scale);
        int vz = (int)floorf(pz[j] * scale);
        // memory-safety clamp (inputs are in [0,1) so this is a no-op)
        vx = min(max(vx, 0), 19);
        vy = min(max(vy, 0), 19);
        vz = min(max(vz, 0), 19);
        int h = (vx * 20 + vy) * 20 + vz;
        atomicAdd(&sx[h], px[j]);
        atomicAdd(&sy[h], py[j]);
        atomicAdd(&sz[h], pz[j]);
        atomicAdd(&cn[h], 1.0f);
    }
}

// Single block, 1024 threads, 8 bins each: exclusive scan of occupancy over
// the 8192 (padded) bins gives the sorted-unique rank; write mean per bin.
__global__ void finalize_kernel(const float* __restrict__ sx,
                                const float* __restrict__ sy,
                                const float* __restrict__ sz,
                                const float* __restrict__ cn,
                                float* __restrict__ out) {
    __shared__ int tsum[1024];
    int t = threadIdx.x;
    int base = t * 8;

    float c[8];
    int occ[8];
    int tot = 0;
    #pragma unroll
    for (int j = 0; j < 8; ++j) {
        int b = base + j;
        c[j] = (b < NBINS) ? cn[b] : 0.0f;
        occ[j] = (c[j] > 0.0f) ? 1 : 0;
        tot += occ[j];
    }
    tsum[t] = tot;
    __syncthreads();

    // Hillis-Steele inclusive scan over 1024 thread totals
    for (int off = 1; off < 1024; off <<= 1) {
        int v = tsum[t];
        int add = (t >= off) ? tsum[t - off] : 0;
        __syncthreads();
        tsum[t] = v + add;
        __syncthreads();
    }
    int r = tsum[t] - tot;   // exclusive prefix for this thread

    #pragma unroll
    for (int j = 0; j < 8; ++j) {
        if (occ[j]) {
            int b = base + j;
            float cnt = c[j];
            out[3 * r + 0] = sx[b] / cnt;
            out[3 * r + 1] = sy[b] / cnt;
            out[3 * r + 2] = sz[b] / cnt;
            ++r;
        }
    }
}

extern "C" void kernel_launch(void* const* d_in, const int* in_sizes, int n_in,
                              void* d_out, int out_size, void* d_ws, size_t ws_size,
                              hipStream_t stream) {
    const float* x = (const float*)d_in[0];
    int N = in_sizes[0] / 3;            // 4,000,000 points
    float* out = (float*)d_out;

    float* sx = (float*)d_ws;
    float* sy = sx + NBINS_PAD;
    float* sz = sy + NBINS_PAD;
    float* cn = sz + NBINS_PAD;

    // zero bin accumulators (ws poisoned 0xAA each call) and full output
    hipMemsetAsync(d_ws, 0, 4 * NBINS_PAD * sizeof(float), stream);
    hipMemsetAsync(d_out, 0, (size_t)out_size * sizeof(float), stream);

    int nthreads = (N + 3) / 4;
    int blocks = (nthreads + 255) / 256;
    accum_kernel<<<blocks, 256, 0, stream>>>(x, N, sx, sy, sz, cn);
    finalize_kernel<<<1, 1024, 0, stream>>>(sx, sy, sz, cn, out);
}

// Round 2
// 249.900 us; speedup vs baseline: 3.3836x; 3.3836x over previous
//
#include <hip/hip_runtime.h>
#include <hip/hip_bf16.h>

// Grid (voxel) mean pooling. x in [0,1)^3, voxel=floor(x*20) -> <=8000 bins.
// Raw hash (vx*20+vy)*20+vz is monotone-lexicographic like the reference's
// shifted hash -> identical grouping AND identical sorted-unique order.
//
// R2: global fp32 atomics were memory-side RMWs (WRITE_SIZE 498MB, 739us).
// Replace with per-block LDS aggregation (128KB dynamic LDS, ds_add_f32),
// non-atomic partial flush (256 x 128KB = 32.8MB), tree reduce, then scan.

#define NBINS 8000
#define NBINS_PAD 8192
#define COMPS 4                         // sx, sy, sz, count (AoS: bin*4+comp)
#define ACC_BLOCKS 256
#define ACC_THREADS 1024
#define LDS_FLOATS (NBINS_PAD * COMPS)  // 32768 floats = 128 KB

__global__ void accum_kernel(const float* __restrict__ x, int N,
                             float* __restrict__ partials) {
    extern __shared__ float lds[];      // [NBINS_PAD * 4]
    const float scale = 20.0f;          // 1.0/0.05 rounds to exactly 20.0f
    int t = threadIdx.x;

    // zero LDS (float4 stores)
    float4* lds4 = (float4*)lds;
    #pragma unroll
    for (int k = 0; k < LDS_FLOATS / 4 / ACC_THREADS; ++k)
        lds4[t + k * ACC_THREADS] = make_float4(0.f, 0.f, 0.f, 0.f);
    __syncthreads();

    // grid-stride over quads of 4 points (3 float4 loads per quad)
    const float4* xv = (const float4*)x;
    long long nquads = ((long long)N + 3) / 4;
    long long gstride = (long long)gridDim.x * ACC_THREADS;
    for (long long q = (long long)blockIdx.x * ACC_THREADS + t; q < nquads;
         q += gstride) {
        float px[4], py[4], pz[4];
        int npts;
        if (q * 4 + 4 <= N) {
            float4 a = xv[3 * q + 0];
            float4 b = xv[3 * q + 1];
            float4 c = xv[3 * q + 2];
            px[0] = a.x; py[0] = a.y; pz[0] = a.z;
            px[1] = a.w; py[1] = b.x; pz[1] = b.y;
            px[2] = b.z; py[2] = b.w; pz[2] = c.x;
            px[3] = c.y; py[3] = c.z; pz[3] = c.w;
            npts = 4;
        } else {
            npts = (int)(N - q * 4);
            for (int j = 0; j < npts; ++j) {
                px[j] = x[3 * (q * 4 + j) + 0];
                py[j] = x[3 * (q * 4 + j) + 1];
                pz[j] = x[3 * (q * 4 + j) + 2];
            }
        }
        #pragma unroll
        for (int j = 0; j < 4; ++j) {
            if (j >= npts) break;
            int vx = (int)floorf(px[j] * scale);
            int vy = (int)floorf(py[j] * scale);
            int vz = (int)floorf(pz[j] * scale);
            vx = min(max(vx, 0), 19);   // safety; no-op for x in [0,1)
            vy = min(max(vy, 0), 19);
            vz = min(max(vz, 0), 19);
            int h = (vx * 20 + vy) * 20 + vz;
            atomicAdd(&lds[h * COMPS + 0], px[j]);   // ds_add_f32
            atomicAdd(&lds[h * COMPS + 1], py[j]);
            atomicAdd(&lds[h * COMPS + 2], pz[j]);
            atomicAdd(&lds[h * COMPS + 3], 1.0f);
        }
    }
    __syncthreads();

    // non-atomic flush: this block's partial slice, coalesced float4 stores
    float4* p4 = (float4*)(partials + (size_t)blockIdx.x * LDS_FLOATS);
    #pragma unroll
    for (int k = 0; k < LDS_FLOATS / 4 / ACC_THREADS; ++k)
        p4[t + k * ACC_THREADS] = lds4[t + k * ACC_THREADS];
}

// sum the ACC_BLOCKS partial slices into bins[32768] (AoS bin*4+comp)
__global__ void reduce_kernel(const float* __restrict__ partials,
                              float* __restrict__ bins, int nslices) {
    int i = blockIdx.x * blockDim.x + threadIdx.x;   // [0, LDS_FLOATS)
    float s = 0.f;
    for (int k = 0; k < nslices; ++k)
        s += partials[(size_t)k * LDS_FLOATS + i];
    bins[i] = s;
}

// single block: occupancy scan over 8192 padded bins -> sorted-unique rank,
// write mean per occupied bin.
__global__ void finalize_kernel(const float* __restrict__ bins,
                                float* __restrict__ out) {
    __shared__ int tsum[1024];
    int t = threadIdx.x;
    int base = t * 8;

    float c[8];
    int occ[8];
    int tot = 0;
    #pragma unroll
    for (int j = 0; j < 8; ++j) {
        int b = base + j;
        c[j] = (b < NBINS) ? bins[b * COMPS + 3] : 0.0f;
        occ[j] = (c[j] > 0.0f) ? 1 : 0;
        tot += occ[j];
    }
    tsum[t] = tot;
    __syncthreads();

    for (int off = 1; off < 1024; off <<= 1) {
        int v = tsum[t];
        int add = (t >= off) ? tsum[t - off] : 0;
        __syncthreads();
        tsum[t] = v + add;
        __syncthreads();
    }
    int r = tsum[t] - tot;

    #pragma unroll
    for (int j = 0; j < 8; ++j) {
        if (occ[j]) {
            int b = base + j;
            float cnt = c[j];
            out[3 * r + 0] = bins[b * COMPS + 0] / cnt;
            out[3 * r + 1] = bins[b * COMPS + 1] / cnt;
            out[3 * r + 2] = bins[b * COMPS + 2] / cnt;
            ++r;
        }
    }
}

extern "C" void kernel_launch(void* const* d_in, const int* in_sizes, int n_in,
                              void* d_out, int out_size, void* d_ws, size_t ws_size,
                              hipStream_t stream) {
    const float* x = (const float*)d_in[0];
    int N = in_sizes[0] / 3;
    float* out = (float*)d_out;

    // ws layout: partials [ACC_BLOCKS * 32768 floats] then bins [32768 floats]
    float* partials = (float*)d_ws;
    float* bins = partials + (size_t)ACC_BLOCKS * LDS_FLOATS;

    // opt into 128 KB dynamic LDS (gfx950 has 160 KB/CU); idempotent
    static_assert(LDS_FLOATS * sizeof(float) == 131072, "lds size");
    hipFuncSetAttribute(reinterpret_cast<const void*>(&accum_kernel),
                        hipFuncAttributeMaxDynamicSharedMemorySize, 131072);

    // rows >= num_unique must be zeros (d_out poisoned 0xAA every call)
    hipMemsetAsync(d_out, 0, (size_t)out_size * sizeof(float), stream);

    accum_kernel<<<ACC_BLOCKS, ACC_THREADS, LDS_FLOATS * sizeof(float), stream>>>(
        x, N, partials);
    reduce_kernel<<<LDS_FLOATS / 256, 256, 0, stream>>>(partials, bins, ACC_BLOCKS);
    finalize_kernel<<<1, 1024, 0, stream>>>(bins, out);
}